// Round 3
// baseline (320.048 us; speedup 1.0000x reference)
//
#include <hip/hip_runtime.h>
#include <hip/hip_bf16.h>

#define BB 16
#define SS 4096
#define CC 512
#define NTOK (BB * SS)
#define BLOCKS_PER_BATCH 64
#define WAVES_PER_BATCH (BLOCKS_PER_BATCH * 4)          // 256
#define TOKS_PER_WAVE (SS / WAVES_PER_BATCH)            // 16
#define STEPS (TOKS_PER_WAVE / 2)                       // 8 (2 tokens pipelined/step)

// Dense branchless version: every row is read (perfectly sequential across
// the device); the mask enters only as a 0/1 multiplier. Each wave handles
// 16 tokens of ONE batch, two adjacent tokens per step (8 KB contiguous,
// 8 float4 loads in flight). Per-wave accumulators, one atomicAdd pair at end.
__global__ __launch_bounds__(256) void tok_loss_kernel(
    const float* __restrict__ logits,
    const float* __restrict__ target,
    const int*   __restrict__ mask,
    float*       __restrict__ acc) {
    const int wave  = threadIdx.x >> 6;
    const int lane  = threadIdx.x & 63;
    const int batch = blockIdx.x / BLOCKS_PER_BATCH;
    const int wib   = (blockIdx.x % BLOCKS_PER_BATCH) * 4 + wave;  // 0..255

    float lossAcc = 0.0f;
    float cntAcc  = 0.0f;

    #pragma unroll
    for (int j = 0; j < STEPS; ++j) {
        const int tokA = batch * SS + j * (WAVES_PER_BATCH * 2) + 2 * wib;
        const int tokB = tokA + 1;

        // masks (wave-broadcast loads)
        const float mA = (mask[tokA] == 1) ? 1.0f : 0.0f;
        const float mB = (mask[tokB] == 1) ? 1.0f : 0.0f;

        // 8 unconditional float4 loads — all issued before any use
        const float4* xpA = (const float4*)(logits + (size_t)tokA * CC);
        const float4* tpA = (const float4*)(target + (size_t)tokA * CC);
        const float4* xpB = (const float4*)(logits + (size_t)tokB * CC);
        const float4* tpB = (const float4*)(target + (size_t)tokB * CC);
        float4 xA0 = xpA[lane];
        float4 xA1 = xpA[lane + 64];
        float4 xB0 = xpB[lane];
        float4 xB1 = xpB[lane + 64];
        float4 tA0 = tpA[lane];
        float4 tA1 = tpA[lane + 64];
        float4 tB0 = tpB[lane];
        float4 tB1 = tpB[lane + 64];

        float seA = __expf(xA0.x) + __expf(xA0.y) + __expf(xA0.z) + __expf(xA0.w)
                  + __expf(xA1.x) + __expf(xA1.y) + __expf(xA1.z) + __expf(xA1.w);
        float seB = __expf(xB0.x) + __expf(xB0.y) + __expf(xB0.z) + __expf(xB0.w)
                  + __expf(xB1.x) + __expf(xB1.y) + __expf(xB1.z) + __expf(xB1.w);
        float dotA = tA0.x * xA0.x + tA0.y * xA0.y + tA0.z * xA0.z + tA0.w * xA0.w
                   + tA1.x * xA1.x + tA1.y * xA1.y + tA1.z * xA1.z + tA1.w * xA1.w;
        float dotB = tB0.x * xB0.x + tB0.y * xB0.y + tB0.z * xB0.z + tB0.w * xB0.w
                   + tB1.x * xB1.x + tB1.y * xB1.y + tB1.z * xB1.z + tB1.w * xB1.w;

        // 4 independent butterfly chains
        #pragma unroll
        for (int off = 32; off >= 1; off >>= 1) {
            seA  += __shfl_xor(seA, off, 64);
            seB  += __shfl_xor(seB, off, 64);
            dotA += __shfl_xor(dotA, off, 64);
            dotB += __shfl_xor(dotB, off, 64);
        }

        lossAcc += mA * (__logf(seA) - dotA) + mB * (__logf(seB) - dotB);
        cntAcc  += mA + mB;
    }

    if (lane == 0) {
        atomicAdd(&acc[2 * batch],     lossAcc);
        atomicAdd(&acc[2 * batch + 1], cntAcc);
    }
}

// One wave reads the 16 (sum,cnt) pairs and produces the scalar.
__global__ __launch_bounds__(64) void finalize_kernel(
    const float* __restrict__ acc,
    float*       __restrict__ out) {
    const int lane = threadIdx.x;
    float pb = 0.0f, has = 0.0f;
    if (lane < BB) {
        float s = acc[2 * lane];
        float c = acc[2 * lane + 1];
        if (c > 0.0f) { pb = s / c; has = 1.0f; }
    }
    #pragma unroll
    for (int off = 32; off >= 1; off >>= 1) {
        pb  += __shfl_xor(pb, off, 64);
        has += __shfl_xor(has, off, 64);
    }
    if (lane == 0) out[0] = pb / fmaxf(has, 1.0f);
}

extern "C" void kernel_launch(void* const* d_in, const int* in_sizes, int n_in,
                              void* d_out, int out_size, void* d_ws, size_t ws_size,
                              hipStream_t stream) {
    const float* logits = (const float*)d_in[0];
    const float* target = (const float*)d_in[1];
    const int*   mask   = (const int*)d_in[2];
    float* out = (float*)d_out;
    float* acc = (float*)d_ws;  // 32 floats

    hipMemsetAsync(acc, 0, 2 * BB * sizeof(float), stream);
    tok_loss_kernel<<<BB * BLOCKS_PER_BATCH, 256, 0, stream>>>(logits, target, mask, acc);
    finalize_kernel<<<1, 64, 0, stream>>>(acc, out);
}

// Round 4
// 265.866 us; speedup vs baseline: 1.2038x; 1.2038x over previous
//
#include <hip/hip_runtime.h>
#include <hip/hip_bf16.h>

#define BB 16
#define SS 4096
#define CC 512
#define NTOK (BB * SS)
#define BLOCKS 2048
#define WAVES (BLOCKS * 4)   // 8192
#define TPW (NTOK / WAVES)   // 8 tokens per wave (consecutive -> one batch)

// Mask-skip, deferred-reduction version.
// Per wave: 8 consecutive tokens. K-loop (4 pairs): conditionally load the
// pair's 8 float4s (4KB/token skipped when masked), accumulate per-lane
// exp-sums (one register per token) and a single per-lane dot accumulator
// (dot is linear -> no per-token reduction). ONE 9-chain interleaved
// butterfly at the end. cnt is wave-uniform from the mask. Block-level LDS
// combine -> 2 atomicAdds per block (2048 blocks over 32 addresses).
__global__ __launch_bounds__(256, 8) void tok_loss_kernel(
    const float* __restrict__ logits,
    const float* __restrict__ target,
    const int*   __restrict__ mask,
    float*       __restrict__ acc) {
    const int wave = threadIdx.x >> 6;
    const int lane = threadIdx.x & 63;
    const int wid  = blockIdx.x * 4 + wave;
    const int tokbase = wid * TPW;
    const int batch   = tokbase / SS;   // TPW divides SS: wave stays in one batch

    const int4 m0 = *(const int4*)(mask + tokbase);
    const int4 m1 = *(const int4*)(mask + tokbase + 4);
    const int act[TPW] = {m0.x == 1, m0.y == 1, m0.z == 1, m0.w == 1,
                          m1.x == 1, m1.y == 1, m1.z == 1, m1.w == 1};

    float sep[TPW];
    #pragma unroll
    for (int i = 0; i < TPW; ++i) sep[i] = 0.0f;
    float dotAcc = 0.0f;
    float cnt = 0.0f;

    #pragma unroll
    for (int j = 0; j < TPW; j += 2) {
        const size_t ra = (size_t)(tokbase + j) * CC;
        const size_t rb = (size_t)(tokbase + j + 1) * CC;
        float4 xa0, xa1, ua0, ua1, xb0, xb1, ub0, ub1;
        // issue both tokens' loads before consuming either (latency overlap)
        if (act[j]) {
            const float4* xp = (const float4*)(logits + ra);
            const float4* tp = (const float4*)(target + ra);
            xa0 = xp[lane]; xa1 = xp[lane + 64];
            ua0 = tp[lane]; ua1 = tp[lane + 64];
        }
        if (act[j + 1]) {
            const float4* xp = (const float4*)(logits + rb);
            const float4* tp = (const float4*)(target + rb);
            xb0 = xp[lane]; xb1 = xp[lane + 64];
            ub0 = tp[lane]; ub1 = tp[lane + 64];
        }
        if (act[j]) {
            sep[j] = __expf(xa0.x) + __expf(xa0.y) + __expf(xa0.z) + __expf(xa0.w)
                   + __expf(xa1.x) + __expf(xa1.y) + __expf(xa1.z) + __expf(xa1.w);
            dotAcc += ua0.x * xa0.x + ua0.y * xa0.y + ua0.z * xa0.z + ua0.w * xa0.w
                    + ua1.x * xa1.x + ua1.y * xa1.y + ua1.z * xa1.z + ua1.w * xa1.w;
            cnt += 1.0f;
        }
        if (act[j + 1]) {
            sep[j + 1] = __expf(xb0.x) + __expf(xb0.y) + __expf(xb0.z) + __expf(xb0.w)
                       + __expf(xb1.x) + __expf(xb1.y) + __expf(xb1.z) + __expf(xb1.w);
            dotAcc += ub0.x * xb0.x + ub0.y * xb0.y + ub0.z * xb0.z + ub0.w * xb0.w
                    + ub1.x * xb1.x + ub1.y * xb1.y + ub1.z * xb1.z + ub1.w * xb1.w;
            cnt += 1.0f;
        }
    }

    // one interleaved butterfly: 9 independent chains, 6 stages
    #pragma unroll
    for (int off = 32; off >= 1; off >>= 1) {
        #pragma unroll
        for (int i = 0; i < TPW; ++i) sep[i] += __shfl_xor(sep[i], off, 64);
        dotAcc += __shfl_xor(dotAcc, off, 64);
    }

    float loss = -dotAcc;
    #pragma unroll
    for (int i = 0; i < TPW; ++i)
        if (act[i]) loss += __logf(sep[i]);

    __shared__ float ls[4], lc[4];
    if (lane == 0) { ls[wave] = loss; lc[wave] = cnt; }
    __syncthreads();
    if (threadIdx.x == 0) {
        atomicAdd(&acc[2 * batch],     ls[0] + ls[1] + ls[2] + ls[3]);
        atomicAdd(&acc[2 * batch + 1], lc[0] + lc[1] + lc[2] + lc[3]);
    }
}

// One wave reads the 16 (sum,cnt) pairs and produces the scalar.
__global__ __launch_bounds__(64) void finalize_kernel(
    const float* __restrict__ acc,
    float*       __restrict__ out) {
    const int lane = threadIdx.x;
    float pb = 0.0f, has = 0.0f;
    if (lane < BB) {
        float s = acc[2 * lane];
        float c = acc[2 * lane + 1];
        if (c > 0.0f) { pb = s / c; has = 1.0f; }
    }
    #pragma unroll
    for (int off = 32; off >= 1; off >>= 1) {
        pb  += __shfl_xor(pb, off, 64);
        has += __shfl_xor(has, off, 64);
    }
    if (lane == 0) out[0] = pb / fmaxf(has, 1.0f);
}

extern "C" void kernel_launch(void* const* d_in, const int* in_sizes, int n_in,
                              void* d_out, int out_size, void* d_ws, size_t ws_size,
                              hipStream_t stream) {
    const float* logits = (const float*)d_in[0];
    const float* target = (const float*)d_in[1];
    const int*   mask   = (const int*)d_in[2];
    float* out = (float*)d_out;
    float* acc = (float*)d_ws;  // 32 floats

    hipMemsetAsync(acc, 0, 2 * BB * sizeof(float), stream);
    tok_loss_kernel<<<BLOCKS, 256, 0, stream>>>(logits, target, mask, acc);
    finalize_kernel<<<1, 64, 0, stream>>>(acc, out);
}